// Round 1
// baseline (491.011 us; speedup 1.0000x reference)
//
#include <hip/hip_runtime.h>
#include <hip/hip_cooperative_groups.h>

namespace cg = cooperative_groups;

static constexpr float kThresh = 0.01f;
static constexpr int TPB     = 256;
static constexpr int NBLK    = 1024;   // 4 blocks/CU x 256 CU; co-residency guaranteed by __launch_bounds__(256,4)
static constexpr int RBLOCKS = 1024;   // fallback stage-1 grid

typedef float f32x4 __attribute__((ext_vector_type(4)));

// Monotone float <-> uint key: k(a) < k(b)  <=>  a < b  (for non-NaN floats)
__device__ __forceinline__ unsigned fkey(float f) {
    unsigned u = __float_as_uint(f);
    return (u & 0x80000000u) ? ~u : (u | 0x80000000u);
}
__device__ __forceinline__ float unkey(unsigned k) {
    unsigned u = (k & 0x80000000u) ? (k & 0x7fffffffu) : ~k;
    return __uint_as_float(u);
}

__device__ __forceinline__ void acc_one(float x, unsigned& smin, unsigned& smax,
                                        unsigned& lmin, unsigned& lmax) {
    unsigned k = fkey(x);
    if (fabsf(x) > kThresh) {
        lmin = min(lmin, k);
        lmax = max(lmax, k);
    } else {
        smin = min(smin, k);
        smax = max(smax, k);
    }
}

__device__ __forceinline__ void acc4(float4 v, unsigned& smin, unsigned& smax,
                                     unsigned& lmin, unsigned& lmax) {
    acc_one(v.x, smin, smax, lmin, lmax);
    acc_one(v.y, smin, smax, lmin, lmax);
    acc_one(v.z, smin, smax, lmin, lmax);
    acc_one(v.w, smin, smax, lmin, lmax);
}

__device__ __forceinline__ void wave_reduce4(unsigned& smin, unsigned& smax,
                                             unsigned& lmin, unsigned& lmax) {
    #pragma unroll
    for (int off = 32; off > 0; off >>= 1) {
        smin = min(smin, (unsigned)__shfl_down((int)smin, off));
        smax = max(smax, (unsigned)__shfl_down((int)smax, off));
        lmin = min(lmin, (unsigned)__shfl_down((int)lmin, off));
        lmax = max(lmax, (unsigned)__shfl_down((int)lmax, off));
    }
}

__device__ __forceinline__ float deq1(float x, float smin, float ssc, float sis, bool sv,
                                      float lmin, float lsc, float lis, bool lv) {
    bool large = fabsf(x) > kThresh;
    float bmin = large ? lmin : smin;
    float sc   = large ? lsc : ssc;
    float is   = large ? lis : sis;
    bool  v    = large ? lv : sv;
    float q = rintf((x - bmin) * sc);          // round((x-bmin)/denom*levels), half-to-even
    float d = fmaf(q, is, bmin);               // q/levels*denom + bmin
    return v ? d : x;
}

// ---------------------------------------------------------------------------
// Fused cooperative kernel: reduce -> grid.sync -> fold -> grid.sync -> dequant
// Partials live in the first 16 KB of `out` (overwritten only after sync #2).
// Agent-scope atomics for the partials: plain stores could sit in a non-
// coherent per-XCD L2 across the grid sync.
// ---------------------------------------------------------------------------
__global__ __launch_bounds__(TPB, 4) void kv_fused(const float* __restrict__ in,
                                                   float* __restrict__ out, int n,
                                                   unsigned* __restrict__ pt) {
    const int n4 = n >> 2;
    const float4* __restrict__ in4 = (const float4*)in;
    const int tid = blockIdx.x * TPB + threadIdx.x;
    const int stride = NBLK * TPB;

    // ---- phase 1: block-local min/max per bin, 2 loads in flight ----
    unsigned smin = 0xFFFFFFFFu, smax = 0u, lmin = 0xFFFFFFFFu, lmax = 0u;
    int i = tid;
    for (; i + stride < n4; i += 2 * stride) {
        float4 a = in4[i];
        float4 b = in4[i + stride];
        acc4(a, smin, smax, lmin, lmax);
        acc4(b, smin, smax, lmin, lmax);
    }
    for (; i < n4; i += stride) acc4(in4[i], smin, smax, lmin, lmax);
    for (int j = (n4 << 2) + tid; j < n; j += stride)
        acc_one(in[j], smin, smax, lmin, lmax);

    wave_reduce4(smin, smax, lmin, lmax);

    __shared__ unsigned ls[4][4];
    __shared__ float sc8[8];
    const int wave = threadIdx.x >> 6;
    if ((threadIdx.x & 63) == 0) {
        ls[wave][0] = smin; ls[wave][1] = smax; ls[wave][2] = lmin; ls[wave][3] = lmax;
    }
    __syncthreads();
    if (threadIdx.x == 0) {
        unsigned a = ls[0][0], b = ls[0][1], c = ls[0][2], d = ls[0][3];
        #pragma unroll
        for (int w = 1; w < 4; ++w) {
            a = min(a, ls[w][0]); b = max(b, ls[w][1]);
            c = min(c, ls[w][2]); d = max(d, ls[w][3]);
        }
        __hip_atomic_store(&pt[blockIdx.x * 4 + 0], a, __ATOMIC_RELAXED, __HIP_MEMORY_SCOPE_AGENT);
        __hip_atomic_store(&pt[blockIdx.x * 4 + 1], b, __ATOMIC_RELAXED, __HIP_MEMORY_SCOPE_AGENT);
        __hip_atomic_store(&pt[blockIdx.x * 4 + 2], c, __ATOMIC_RELAXED, __HIP_MEMORY_SCOPE_AGENT);
        __hip_atomic_store(&pt[blockIdx.x * 4 + 3], d, __ATOMIC_RELAXED, __HIP_MEMORY_SCOPE_AGENT);
    }

    cg::this_grid().sync();

    // ---- fold: every block redundantly reduces all NBLK partial sets (16 KB, L2) ----
    unsigned fa = 0xFFFFFFFFu, fb = 0u, fc = 0xFFFFFFFFu, fd = 0u;
    for (int p = threadIdx.x; p < NBLK; p += TPB) {
        fa = min(fa, __hip_atomic_load(&pt[4 * p + 0], __ATOMIC_RELAXED, __HIP_MEMORY_SCOPE_AGENT));
        fb = max(fb, __hip_atomic_load(&pt[4 * p + 1], __ATOMIC_RELAXED, __HIP_MEMORY_SCOPE_AGENT));
        fc = min(fc, __hip_atomic_load(&pt[4 * p + 2], __ATOMIC_RELAXED, __HIP_MEMORY_SCOPE_AGENT));
        fd = max(fd, __hip_atomic_load(&pt[4 * p + 3], __ATOMIC_RELAXED, __HIP_MEMORY_SCOPE_AGENT));
    }
    wave_reduce4(fa, fb, fc, fd);
    if ((threadIdx.x & 63) == 0) {
        ls[wave][0] = fa; ls[wave][1] = fb; ls[wave][2] = fc; ls[wave][3] = fd;
    }
    __syncthreads();
    if (threadIdx.x == 0) {
        unsigned a = ls[0][0], b = ls[0][1], c = ls[0][2], d = ls[0][3];
        #pragma unroll
        for (int w = 1; w < 4; ++w) {
            a = min(a, ls[w][0]); b = max(b, ls[w][1]);
            c = min(c, ls[w][2]); d = max(d, ls[w][3]);
        }
        bool sv = a < b;               // valid = has_any && (bmax != bmin)
        bool lv = c < d;
        float smn  = unkey(a);
        float sden = sv ? (unkey(b) - smn) : 1.0f;
        float lmn  = unkey(c);
        float lden = lv ? (unkey(d) - lmn) : 1.0f;
        sc8[0] = smn; sc8[1] = 15.0f / sden;  sc8[2] = sden / 15.0f;
        sc8[3] = lmn; sc8[4] = 255.0f / lden; sc8[5] = lden / 255.0f;
        sc8[6] = sv ? 1.0f : 0.0f;
        sc8[7] = lv ? 1.0f : 0.0f;
    }
    __syncthreads();
    const float smn = sc8[0], ssc = sc8[1], sis = sc8[2];
    const float lmn = sc8[3], lsc = sc8[4], lis = sc8[5];
    const bool  sv  = sc8[6] != 0.0f, lv = sc8[7] != 0.0f;

    cg::this_grid().sync();   // all partial reads done before out[] is overwritten

    // ---- phase 2: dequant; nontemporal stores keep the input L3-resident ----
    float4* __restrict__ out4 = (float4*)out;
    int k = tid;
    for (; k + stride < n4; k += 2 * stride) {
        float4 a = in4[k];
        float4 b = in4[k + stride];
        f32x4 ra, rb;
        ra.x = deq1(a.x, smn, ssc, sis, sv, lmn, lsc, lis, lv);
        ra.y = deq1(a.y, smn, ssc, sis, sv, lmn, lsc, lis, lv);
        ra.z = deq1(a.z, smn, ssc, sis, sv, lmn, lsc, lis, lv);
        ra.w = deq1(a.w, smn, ssc, sis, sv, lmn, lsc, lis, lv);
        rb.x = deq1(b.x, smn, ssc, sis, sv, lmn, lsc, lis, lv);
        rb.y = deq1(b.y, smn, ssc, sis, sv, lmn, lsc, lis, lv);
        rb.z = deq1(b.z, smn, ssc, sis, sv, lmn, lsc, lis, lv);
        rb.w = deq1(b.w, smn, ssc, sis, sv, lmn, lsc, lis, lv);
        __builtin_nontemporal_store(ra, (f32x4*)&out4[k]);
        __builtin_nontemporal_store(rb, (f32x4*)&out4[k + stride]);
    }
    for (; k < n4; k += stride) {
        float4 a = in4[k];
        f32x4 r;
        r.x = deq1(a.x, smn, ssc, sis, sv, lmn, lsc, lis, lv);
        r.y = deq1(a.y, smn, ssc, sis, sv, lmn, lsc, lis, lv);
        r.z = deq1(a.z, smn, ssc, sis, sv, lmn, lsc, lis, lv);
        r.w = deq1(a.w, smn, ssc, sis, sv, lmn, lsc, lis, lv);
        __builtin_nontemporal_store(r, (f32x4*)&out4[k]);
    }
    for (int j = (n4 << 2) + tid; j < n; j += stride)
        out[j] = deq1(in[j], smn, ssc, sis, sv, lmn, lsc, lis, lv);
}

// ---------------------------------------------------------------------------
// Fallback path (non-cooperative), identical to the previously-verified kernel.
// ---------------------------------------------------------------------------
__global__ __launch_bounds__(256) void kv_partial(const float* __restrict__ in, int n,
                                                  unsigned* __restrict__ partials) {
    unsigned smin = 0xFFFFFFFFu, smax = 0u, lmin = 0xFFFFFFFFu, lmax = 0u;
    const int n4 = n >> 2;
    const float4* __restrict__ in4 = (const float4*)in;
    const int stride = gridDim.x * blockDim.x;
    for (int i = blockIdx.x * blockDim.x + threadIdx.x; i < n4; i += stride) {
        float4 v = in4[i];
        acc4(v, smin, smax, lmin, lmax);
    }
    for (int i = (n4 << 2) + blockIdx.x * blockDim.x + threadIdx.x; i < n; i += stride) {
        acc_one(in[i], smin, smax, lmin, lmax);
    }
    wave_reduce4(smin, smax, lmin, lmax);

    __shared__ unsigned ls[4][4];
    const int wave = threadIdx.x >> 6;
    if ((threadIdx.x & 63) == 0) {
        ls[wave][0] = smin; ls[wave][1] = smax; ls[wave][2] = lmin; ls[wave][3] = lmax;
    }
    __syncthreads();
    if (threadIdx.x == 0) {
        unsigned a = ls[0][0], b = ls[0][1], c = ls[0][2], d = ls[0][3];
        #pragma unroll
        for (int w = 1; w < 4; ++w) {
            a = min(a, ls[w][0]); b = max(b, ls[w][1]);
            c = min(c, ls[w][2]); d = max(d, ls[w][3]);
        }
        partials[blockIdx.x * 4 + 0] = a;
        partials[blockIdx.x * 4 + 1] = b;
        partials[blockIdx.x * 4 + 2] = c;
        partials[blockIdx.x * 4 + 3] = d;
    }
}

__global__ __launch_bounds__(256) void kv_final(const unsigned* __restrict__ partials,
                                                unsigned* __restrict__ ws) {
    unsigned smin = 0xFFFFFFFFu, smax = 0u, lmin = 0xFFFFFFFFu, lmax = 0u;
    for (int i = threadIdx.x; i < RBLOCKS; i += 256) {
        smin = min(smin, partials[4 * i + 0]);
        smax = max(smax, partials[4 * i + 1]);
        lmin = min(lmin, partials[4 * i + 2]);
        lmax = max(lmax, partials[4 * i + 3]);
    }
    wave_reduce4(smin, smax, lmin, lmax);

    __shared__ unsigned ls[4][4];
    const int wave = threadIdx.x >> 6;
    if ((threadIdx.x & 63) == 0) {
        ls[wave][0] = smin; ls[wave][1] = smax; ls[wave][2] = lmin; ls[wave][3] = lmax;
    }
    __syncthreads();
    if (threadIdx.x == 0) {
        unsigned a = ls[0][0], b = ls[0][1], c = ls[0][2], d = ls[0][3];
        #pragma unroll
        for (int w = 1; w < 4; ++w) {
            a = min(a, ls[w][0]); b = max(b, ls[w][1]);
            c = min(c, ls[w][2]); d = max(d, ls[w][3]);
        }
        ws[0] = a; ws[1] = b; ws[2] = c; ws[3] = d;
    }
}

__global__ __launch_bounds__(256) void kv_dequant(const float* __restrict__ in,
                                                  float* __restrict__ out, int n,
                                                  const unsigned* __restrict__ ws) {
    const unsigned sk0 = ws[0], sk1 = ws[1], lk0 = ws[2], lk1 = ws[3];
    const bool sv = sk0 < sk1;
    const bool lv = lk0 < lk1;
    const float smin = unkey(sk0);
    const float sden = sv ? (unkey(sk1) - smin) : 1.0f;
    const float lmin = unkey(lk0);
    const float lden = lv ? (unkey(lk1) - lmin) : 1.0f;
    const float ssc = 15.0f / sden,  sis = sden / 15.0f;
    const float lsc = 255.0f / lden, lis = lden / 255.0f;

    const int n4 = n >> 2;
    const int i = blockIdx.x * blockDim.x + threadIdx.x;
    const float4* __restrict__ in4 = (const float4*)in;
    float4* __restrict__ out4 = (float4*)out;
    if (i < n4) {
        float4 v = in4[i];
        float4 r;
        r.x = deq1(v.x, smin, ssc, sis, sv, lmin, lsc, lis, lv);
        r.y = deq1(v.y, smin, ssc, sis, sv, lmin, lsc, lis, lv);
        r.z = deq1(v.z, smin, ssc, sis, sv, lmin, lsc, lis, lv);
        r.w = deq1(v.w, smin, ssc, sis, sv, lmin, lsc, lis, lv);
        out4[i] = r;
    }
    const int tail = n - (n4 << 2);
    if (i < tail) {
        int j = (n4 << 2) + i;
        out[j] = deq1(in[j], smin, ssc, sis, sv, lmin, lsc, lis, lv);
    }
}

extern "C" void kernel_launch(void* const* d_in, const int* in_sizes, int n_in,
                              void* d_out, int out_size, void* d_ws, size_t ws_size,
                              hipStream_t stream) {
    const float* in = (const float*)d_in[0];
    float* out = (float*)d_out;
    unsigned* ws = (unsigned*)d_ws;
    const int n = in_sizes[0];

    // Partials staged in the first 16 KB of d_out; the fused kernel only
    // overwrites them after the second grid sync, and the fallback path's
    // dequant pass overwrites all of d_out afterwards anyway.
    unsigned* pt = (unsigned*)d_out;

    void* args[] = { (void*)&in, (void*)&out, (void*)&n, (void*)&pt };
    hipError_t err = hipLaunchCooperativeKernel((void*)kv_fused, dim3(NBLK), dim3(TPB),
                                                args, 0, stream);
    if (err != hipSuccess) {
        (void)hipGetLastError();   // clear error state; fall back to 3-kernel path
        kv_partial<<<RBLOCKS, 256, 0, stream>>>(in, n, pt);
        kv_final<<<1, 256, 0, stream>>>(pt, ws);
        const int n4 = n >> 2;
        int dblocks = (n4 + 255) / 256;
        if (dblocks < 1) dblocks = 1;
        kv_dequant<<<dblocks, 256, 0, stream>>>(in, out, n, ws);
    }
}

// Round 2
// 255.550 us; speedup vs baseline: 1.9214x; 1.9214x over previous
//
#include <hip/hip_runtime.h>

static constexpr float kThresh = 0.01f;
static constexpr int TPB     = 256;
static constexpr int PBLOCKS = 2048;   // stage-1 grid => 2048 partial sets (32 KB)
static constexpr int DBLOCKS = 2048;   // dequant grid (8 blocks/CU, grid-stride)

// Monotone float <-> uint key: k(a) < k(b)  <=>  a < b  (for non-NaN floats)
__device__ __forceinline__ unsigned fkey(float f) {
    unsigned u = __float_as_uint(f);
    return (u & 0x80000000u) ? ~u : (u | 0x80000000u);
}
__device__ __forceinline__ float unkey(unsigned k) {
    unsigned u = (k & 0x80000000u) ? (k & 0x7fffffffu) : ~k;
    return __uint_as_float(u);
}

__device__ __forceinline__ void acc_one(float x, unsigned& smin, unsigned& smax,
                                        unsigned& lmin, unsigned& lmax) {
    unsigned k = fkey(x);
    if (fabsf(x) > kThresh) {
        lmin = min(lmin, k);
        lmax = max(lmax, k);
    } else {
        smin = min(smin, k);
        smax = max(smax, k);
    }
}

__device__ __forceinline__ void acc4(float4 v, unsigned& smin, unsigned& smax,
                                     unsigned& lmin, unsigned& lmax) {
    acc_one(v.x, smin, smax, lmin, lmax);
    acc_one(v.y, smin, smax, lmin, lmax);
    acc_one(v.z, smin, smax, lmin, lmax);
    acc_one(v.w, smin, smax, lmin, lmax);
}

__device__ __forceinline__ void wave_reduce4(unsigned& smin, unsigned& smax,
                                             unsigned& lmin, unsigned& lmax) {
    #pragma unroll
    for (int off = 32; off > 0; off >>= 1) {
        smin = min(smin, (unsigned)__shfl_down((int)smin, off));
        smax = max(smax, (unsigned)__shfl_down((int)smax, off));
        lmin = min(lmin, (unsigned)__shfl_down((int)lmin, off));
        lmax = max(lmax, (unsigned)__shfl_down((int)lmax, off));
    }
}

__device__ __forceinline__ float deq1(float x, float smin, float ssc, float sis, bool sv,
                                      float lmin, float lsc, float lis, bool lv) {
    bool large = fabsf(x) > kThresh;
    float bmin = large ? lmin : smin;
    float sc   = large ? lsc : ssc;
    float is   = large ? lis : sis;
    bool  v    = large ? lv : sv;
    float q = rintf((x - bmin) * sc);          // round((x-bmin)/denom*levels), half-to-even
    float d = fmaf(q, is, bmin);               // q/levels*denom + bmin
    return v ? d : x;
}

// ---------------------------------------------------------------------------
// Stage 1: per-block min/max partials. 4 independent float4 loads in flight
// per thread (64 KB/CU in flight at 8 blocks/CU — covers ~900cy HBM latency).
// ---------------------------------------------------------------------------
__global__ __launch_bounds__(TPB) void kv_partial(const float* __restrict__ in, int n,
                                                  unsigned* __restrict__ partials) {
    unsigned smin = 0xFFFFFFFFu, smax = 0u, lmin = 0xFFFFFFFFu, lmax = 0u;
    const int n4 = n >> 2;
    const float4* __restrict__ in4 = (const float4*)in;
    const int stride = gridDim.x * TPB;
    int i = blockIdx.x * TPB + threadIdx.x;
    for (; i + 3 * stride < n4; i += 4 * stride) {
        float4 a = in4[i];
        float4 b = in4[i + stride];
        float4 c = in4[i + 2 * stride];
        float4 d = in4[i + 3 * stride];
        acc4(a, smin, smax, lmin, lmax);
        acc4(b, smin, smax, lmin, lmax);
        acc4(c, smin, smax, lmin, lmax);
        acc4(d, smin, smax, lmin, lmax);
    }
    for (; i < n4; i += stride) acc4(in4[i], smin, smax, lmin, lmax);
    for (int j = (n4 << 2) + blockIdx.x * TPB + threadIdx.x; j < n; j += stride)
        acc_one(in[j], smin, smax, lmin, lmax);

    wave_reduce4(smin, smax, lmin, lmax);

    __shared__ unsigned ls[4][4];
    const int wave = threadIdx.x >> 6;
    if ((threadIdx.x & 63) == 0) {
        ls[wave][0] = smin; ls[wave][1] = smax; ls[wave][2] = lmin; ls[wave][3] = lmax;
    }
    __syncthreads();
    if (threadIdx.x == 0) {
        unsigned a = ls[0][0], b = ls[0][1], c = ls[0][2], d = ls[0][3];
        #pragma unroll
        for (int w = 1; w < 4; ++w) {
            a = min(a, ls[w][0]); b = max(b, ls[w][1]);
            c = min(c, ls[w][2]); d = max(d, ls[w][3]);
        }
        partials[blockIdx.x * 4 + 0] = a;
        partials[blockIdx.x * 4 + 1] = b;
        partials[blockIdx.x * 4 + 2] = c;
        partials[blockIdx.x * 4 + 3] = d;
    }
}

// ---------------------------------------------------------------------------
// Fallback-only: fold PBLOCKS partial sets into ws[0..3] (one block).
// ---------------------------------------------------------------------------
__global__ __launch_bounds__(TPB) void kv_final(const unsigned* __restrict__ partials,
                                                unsigned* __restrict__ ws) {
    unsigned smin = 0xFFFFFFFFu, smax = 0u, lmin = 0xFFFFFFFFu, lmax = 0u;
    for (int i = threadIdx.x; i < PBLOCKS; i += TPB) {
        smin = min(smin, partials[4 * i + 0]);
        smax = max(smax, partials[4 * i + 1]);
        lmin = min(lmin, partials[4 * i + 2]);
        lmax = max(lmax, partials[4 * i + 3]);
    }
    wave_reduce4(smin, smax, lmin, lmax);

    __shared__ unsigned ls[4][4];
    const int wave = threadIdx.x >> 6;
    if ((threadIdx.x & 63) == 0) {
        ls[wave][0] = smin; ls[wave][1] = smax; ls[wave][2] = lmin; ls[wave][3] = lmax;
    }
    __syncthreads();
    if (threadIdx.x == 0) {
        unsigned a = ls[0][0], b = ls[0][1], c = ls[0][2], d = ls[0][3];
        #pragma unroll
        for (int w = 1; w < 4; ++w) {
            a = min(a, ls[w][0]); b = max(b, ls[w][1]);
            c = min(c, ls[w][2]); d = max(d, ls[w][3]);
        }
        ws[0] = a; ws[1] = b; ws[2] = c; ws[3] = d;
    }
}

// ---------------------------------------------------------------------------
// Stage 2: each block folds `pcount` partial sets (L2-resident, ~32 KB), then
// dequantizes its grid-stride portion. pcount==1 => partials is ws[0..3].
// ---------------------------------------------------------------------------
__global__ __launch_bounds__(TPB) void kv_dequant(const float* __restrict__ in,
                                                  float* __restrict__ out, int n,
                                                  const unsigned* __restrict__ partials,
                                                  int pcount) {
    // ---- fold prologue ----
    unsigned fa = 0xFFFFFFFFu, fb = 0u, fc = 0xFFFFFFFFu, fd = 0u;
    for (int p = threadIdx.x; p < pcount; p += TPB) {
        fa = min(fa, partials[4 * p + 0]);
        fb = max(fb, partials[4 * p + 1]);
        fc = min(fc, partials[4 * p + 2]);
        fd = max(fd, partials[4 * p + 3]);
    }
    wave_reduce4(fa, fb, fc, fd);

    __shared__ unsigned ls[4][4];
    __shared__ float sc8[8];
    const int wave = threadIdx.x >> 6;
    if ((threadIdx.x & 63) == 0) {
        ls[wave][0] = fa; ls[wave][1] = fb; ls[wave][2] = fc; ls[wave][3] = fd;
    }
    __syncthreads();
    if (threadIdx.x == 0) {
        unsigned a = ls[0][0], b = ls[0][1], c = ls[0][2], d = ls[0][3];
        #pragma unroll
        for (int w = 1; w < 4; ++w) {
            a = min(a, ls[w][0]); b = max(b, ls[w][1]);
            c = min(c, ls[w][2]); d = max(d, ls[w][3]);
        }
        bool sv = a < b;               // valid = has_any && (bmax != bmin)
        bool lv = c < d;
        float smn  = unkey(a);
        float sden = sv ? (unkey(b) - smn) : 1.0f;
        float lmn  = unkey(c);
        float lden = lv ? (unkey(d) - lmn) : 1.0f;
        sc8[0] = smn; sc8[1] = 15.0f / sden;  sc8[2] = sden / 15.0f;
        sc8[3] = lmn; sc8[4] = 255.0f / lden; sc8[5] = lden / 255.0f;
        sc8[6] = sv ? 1.0f : 0.0f;
        sc8[7] = lv ? 1.0f : 0.0f;
    }
    __syncthreads();
    const float smn = sc8[0], ssc = sc8[1], sis = sc8[2];
    const float lmn = sc8[3], lsc = sc8[4], lis = sc8[5];
    const bool  sv  = sc8[6] != 0.0f, lv = sc8[7] != 0.0f;

    // ---- dequant: 4 independent float4 loads in flight, plain stores ----
    const int n4 = n >> 2;
    const float4* __restrict__ in4 = (const float4*)in;
    float4* __restrict__ out4 = (float4*)out;
    const int stride = gridDim.x * TPB;
    int k = blockIdx.x * TPB + threadIdx.x;
    for (; k + 3 * stride < n4; k += 4 * stride) {
        float4 a = in4[k];
        float4 b = in4[k + stride];
        float4 c = in4[k + 2 * stride];
        float4 d = in4[k + 3 * stride];
        float4 ra, rb, rc, rd;
        ra.x = deq1(a.x, smn, ssc, sis, sv, lmn, lsc, lis, lv);
        ra.y = deq1(a.y, smn, ssc, sis, sv, lmn, lsc, lis, lv);
        ra.z = deq1(a.z, smn, ssc, sis, sv, lmn, lsc, lis, lv);
        ra.w = deq1(a.w, smn, ssc, sis, sv, lmn, lsc, lis, lv);
        rb.x = deq1(b.x, smn, ssc, sis, sv, lmn, lsc, lis, lv);
        rb.y = deq1(b.y, smn, ssc, sis, sv, lmn, lsc, lis, lv);
        rb.z = deq1(b.z, smn, ssc, sis, sv, lmn, lsc, lis, lv);
        rb.w = deq1(b.w, smn, ssc, sis, sv, lmn, lsc, lis, lv);
        rc.x = deq1(c.x, smn, ssc, sis, sv, lmn, lsc, lis, lv);
        rc.y = deq1(c.y, smn, ssc, sis, sv, lmn, lsc, lis, lv);
        rc.z = deq1(c.z, smn, ssc, sis, sv, lmn, lsc, lis, lv);
        rc.w = deq1(c.w, smn, ssc, sis, sv, lmn, lsc, lis, lv);
        rd.x = deq1(d.x, smn, ssc, sis, sv, lmn, lsc, lis, lv);
        rd.y = deq1(d.y, smn, ssc, sis, sv, lmn, lsc, lis, lv);
        rd.z = deq1(d.z, smn, ssc, sis, sv, lmn, lsc, lis, lv);
        rd.w = deq1(d.w, smn, ssc, sis, sv, lmn, lsc, lis, lv);
        out4[k]              = ra;
        out4[k + stride]     = rb;
        out4[k + 2 * stride] = rc;
        out4[k + 3 * stride] = rd;
    }
    for (; k < n4; k += stride) {
        float4 a = in4[k];
        float4 r;
        r.x = deq1(a.x, smn, ssc, sis, sv, lmn, lsc, lis, lv);
        r.y = deq1(a.y, smn, ssc, sis, sv, lmn, lsc, lis, lv);
        r.z = deq1(a.z, smn, ssc, sis, sv, lmn, lsc, lis, lv);
        r.w = deq1(a.w, smn, ssc, sis, sv, lmn, lsc, lis, lv);
        out4[k] = r;
    }
    for (int j = (n4 << 2) + blockIdx.x * TPB + threadIdx.x; j < n; j += stride)
        out[j] = deq1(in[j], smn, ssc, sis, sv, lmn, lsc, lis, lv);
}

extern "C" void kernel_launch(void* const* d_in, const int* in_sizes, int n_in,
                              void* d_out, int out_size, void* d_ws, size_t ws_size,
                              hipStream_t stream) {
    const float* in = (const float*)d_in[0];
    float* out = (float*)d_out;
    unsigned* ws = (unsigned*)d_ws;
    const int n = in_sizes[0];

    if (ws_size >= (size_t)(PBLOCKS * 4) * sizeof(unsigned)) {
        // 2-kernel path: partials live in the workspace (safe from overwrite).
        unsigned* pt = ws;
        kv_partial<<<PBLOCKS, TPB, 0, stream>>>(in, n, pt);
        kv_dequant<<<DBLOCKS, TPB, 0, stream>>>(in, out, n, pt, PBLOCKS);
    } else {
        // 3-kernel fallback: stage partials in d_out, fold into ws[0..3] first.
        // (Safe: kv_final reads them before kv_dequant writes d_out.)
        unsigned* pt = (unsigned*)d_out;
        kv_partial<<<PBLOCKS, TPB, 0, stream>>>(in, n, pt);
        kv_final<<<1, TPB, 0, stream>>>(pt, ws);
        kv_dequant<<<DBLOCKS, TPB, 0, stream>>>(in, out, n, ws, 1);
    }
}